// Round 1
// baseline (594.860 us; speedup 1.0000x reference)
//
#include <hip/hip_runtime.h>
#include <math.h>

// Problem constants
#define BB 2
#define CC 64
#define NN 9216           // 96*96
#define C8 8

// Workspace layout (floats)
#define WS_Q     0            // [B][N][8]
#define WS_K     147456       // [B][N][8]
#define WS_V     294912       // [B][N][64]   (n-major: row n holds 64 channels)
#define WS_MX    1474560      // [B*N]
#define WS_RI    1492992      // [B*N]
#define WS_MP    1511424      // [8][B*N] partial max
#define WS_DP    1658880      // [8][B*N] partial sumexp
// total = 1806336 floats = 7.2 MB

__device__ __forceinline__ float dot8(float4 a0, float4 a1, float4 b0, float4 b1) {
    return a0.x*b0.x + a0.y*b0.y + a0.z*b0.z + a0.w*b0.w
         + a1.x*b1.x + a1.y*b1.y + a1.z*b1.z + a1.w*b1.w;
}

// ---------------- Kernel 1: QKV projections ----------------
// grid (36, 2), block 256. Thread owns one spatial position n.
__global__ __launch_bounds__(256) void qkv_kernel(
    const float* __restrict__ x,
    const float* __restrict__ Wq, const float* __restrict__ bq,
    const float* __restrict__ Wk, const float* __restrict__ bk,
    const float* __restrict__ Wv, const float* __restrict__ bv,
    float* __restrict__ Q, float* __restrict__ K, float* __restrict__ V)
{
    __shared__ float wq[8*64], wk[8*64], wv[64*64], bqs[8], bks[8], bvs[64];
    int tid = threadIdx.x;
    for (int i = tid; i < 512; i += 256) { wq[i] = Wq[i]; wk[i] = Wk[i]; }
    for (int i = tid; i < 4096; i += 256) wv[i] = Wv[i];
    if (tid < 8)  { bqs[tid] = bq[tid]; bks[tid] = bk[tid]; }
    if (tid < 64) { bvs[tid] = bv[tid]; }
    __syncthreads();

    int b = blockIdx.y;
    int n = blockIdx.x * 256 + tid;

    float xc[64];
    #pragma unroll
    for (int c = 0; c < 64; c++) xc[c] = x[(b*64 + c)*NN + n];

    float q[8], k[8];
    #pragma unroll
    for (int o = 0; o < 8; o++) { q[o] = bqs[o]; k[o] = bks[o]; }
    #pragma unroll
    for (int c = 0; c < 64; c++) {
        float xv = xc[c];
        #pragma unroll
        for (int o = 0; o < 8; o++) {
            q[o] = fmaf(wq[o*64+c], xv, q[o]);
            k[o] = fmaf(wk[o*64+c], xv, k[o]);
        }
    }
    #pragma unroll
    for (int o = 0; o < 8; o++) {
        Q[(b*NN + n)*8 + o] = q[o];
        K[(b*NN + n)*8 + o] = k[o];
    }

    float v[64];
    #pragma unroll
    for (int o = 0; o < 64; o++) v[o] = bvs[o];
    #pragma unroll
    for (int c = 0; c < 64; c++) {
        float xv = xc[c];
        #pragma unroll
        for (int o = 0; o < 64; o++) v[o] = fmaf(wv[o*64+c], xv, v[o]);
    }
    #pragma unroll
    for (int o = 0; o < 64; o++) V[(b*NN + n)*64 + o] = v[o];
}

// ---------------- Kernel 2: column max / sumexp partials ----------------
// grid (36, 2, 8), block 256. Thread owns key-column n; split z covers 1152 query rows m.
__global__ __launch_bounds__(256) void md_kernel(
    const float* __restrict__ Q, const float* __restrict__ K,
    float* __restrict__ Mp, float* __restrict__ Dp)
{
    __shared__ float4 qs[576*2];   // 576 rows x 8 floats
    int tid = threadIdx.x;
    int b = blockIdx.y, s = blockIdx.z;
    int n = blockIdx.x*256 + tid;

    const float4* krow = (const float4*)(K + (size_t)(b*NN + n)*8);
    float4 k0 = krow[0], k1 = krow[1];

    float M = -1e30f, D = 0.0f;

    for (int tile = 0; tile < 2; tile++) {
        int m0 = s*1152 + tile*576;
        __syncthreads();
        const float4* qg = (const float4*)(Q + (size_t)(b*NN + m0)*8);
        for (int i = tid; i < 1152; i += 256) qs[i] = qg[i];
        __syncthreads();

        for (int mm = 0; mm < 576; mm += 8) {
            float e[8];
            #pragma unroll
            for (int j = 0; j < 8; j++) {
                float4 q0 = qs[2*(mm+j)], q1 = qs[2*(mm+j)+1];
                e[j] = dot8(q0, q1, k0, k1);
            }
            float cmax = fmaxf(fmaxf(fmaxf(e[0],e[1]), fmaxf(e[2],e[3])),
                               fmaxf(fmaxf(e[4],e[5]), fmaxf(e[6],e[7])));
            float nM = fmaxf(M, cmax);
            float sum = 0.0f;
            #pragma unroll
            for (int j = 0; j < 8; j++) sum += __expf(e[j] - nM);
            D = D * __expf(M - nM) + sum;
            M = nM;
        }
    }
    Mp[(size_t)s*(2*NN) + b*NN + n] = M;
    Dp[(size_t)s*(2*NN) + b*NN + n] = D;
}

// ---------------- Kernel 3: merge partials ----------------
// grid 72, block 256 over B*N columns
__global__ __launch_bounds__(256) void merge_kernel(
    const float* __restrict__ Mp, const float* __restrict__ Dp,
    float* __restrict__ Mx, float* __restrict__ Ri)
{
    int idx = blockIdx.x*256 + threadIdx.x;   // b*N + n
    float M = -1e30f;
    #pragma unroll
    for (int s = 0; s < 8; s++) M = fmaxf(M, Mp[(size_t)s*(2*NN) + idx]);
    float D = 0.0f;
    #pragma unroll
    for (int s = 0; s < 8; s++)
        D += Dp[(size_t)s*(2*NN) + idx] * __expf(Mp[(size_t)s*(2*NN) + idx] - M);
    Mx[idx] = M;
    Ri[idx] = 1.0f / D;
}

// ---------------- Kernel 4: out = x ----------------
__global__ __launch_bounds__(256) void init_kernel(
    const float* __restrict__ x, float* __restrict__ out)
{
    int i = blockIdx.x*256 + threadIdx.x;    // over 294912 float4
    ((float4*)out)[i] = ((const float4*)x)[i];
}

// ---------------- Kernel 5: fused p + PV ----------------
// grid (144, 2, 4), block 256. Block owns 64 m's; split z owns 2304 n's (36 tiles of 64).
__global__ __launch_bounds__(256) void pv_kernel(
    const float* __restrict__ Q, const float* __restrict__ K,
    const float* __restrict__ V, const float* __restrict__ Mx,
    const float* __restrict__ Ri, const float* __restrict__ gamma_p,
    float* __restrict__ out)
{
    __shared__ float4 kt[64*2];    // [n][8]
    __shared__ float4 vt[64*16];   // [n][64]
    __shared__ float4 pt[64*16];   // [n][64]  p transposed: row n, col m
    __shared__ float  mxs[64], ris[64];

    int tid = threadIdx.x;
    int b = blockIdx.y, s = blockIdx.z;
    int mbase = blockIdx.x * 64;
    float gamma = gamma_p[0];

    // phase-1 identity: this thread computes p for global row m1, 16 local n's
    int m1 = mbase + (tid & 63);
    const float4* qg = (const float4*)(Q + (size_t)(b*NN + m1)*8);
    float4 q0 = qg[0], q1 = qg[1];
    int nloc0 = (tid >> 6) * 16;

    // phase-2 identity
    int mt = tid & 15;      // m quad: mbase + mt*4 .. +3
    int cg = tid >> 4;      // c quad: cg*4 .. +3
    float acc[4][4] = {{0.f}};

    for (int t = 0; t < 36; t++) {
        int n0 = s*2304 + t*64;
        __syncthreads();
        if (tid < 128) kt[tid] = ((const float4*)(K + (size_t)(b*NN + n0)*8))[tid];
        const float4* vg = (const float4*)(V + (size_t)(b*NN + n0)*64);
        #pragma unroll
        for (int i = 0; i < 4; i++) vt[tid + i*256] = vg[tid + i*256];
        if (tid < 64) { mxs[tid] = Mx[b*NN + n0 + tid]; ris[tid] = Ri[b*NN + n0 + tid]; }
        __syncthreads();

        // phase 1: p tile (each (n,m) computed exactly once)
        #pragma unroll
        for (int j = 0; j < 16; j++) {
            int n = nloc0 + j;
            float4 k0 = kt[2*n], k1 = kt[2*n+1];
            float e = dot8(q0, q1, k0, k1);
            float p = __expf(e - mxs[n]) * ris[n];
            ((float*)pt)[n*64 + (tid & 63)] = p;
        }
        __syncthreads();

        // phase 2: acc[mi][ci] += p[n][m] * v[n][c]
        #pragma unroll 8
        for (int nn = 0; nn < 64; nn++) {
            float4 vv = vt[nn*16 + cg];
            float4 pp = pt[nn*16 + mt];
            float pe[4] = {pp.x, pp.y, pp.z, pp.w};
            float ve[4] = {vv.x, vv.y, vv.z, vv.w};
            #pragma unroll
            for (int mi = 0; mi < 4; mi++)
                #pragma unroll
                for (int ci = 0; ci < 4; ci++)
                    acc[mi][ci] = fmaf(pe[mi], ve[ci], acc[mi][ci]);
        }
    }

    // epilogue: out += gamma * acc (out pre-initialized to x)
    #pragma unroll
    for (int mi = 0; mi < 4; mi++) {
        int m = mbase + mt*4 + mi;
        #pragma unroll
        for (int ci = 0; ci < 4; ci++) {
            int c = cg*4 + ci;
            atomicAdd(out + (size_t)(b*64 + c)*NN + m, gamma * acc[mi][ci]);
        }
    }
}

extern "C" void kernel_launch(void* const* d_in, const int* in_sizes, int n_in,
                              void* d_out, int out_size, void* d_ws, size_t ws_size,
                              hipStream_t stream) {
    const float* x     = (const float*)d_in[0];
    const float* Wq    = (const float*)d_in[1];
    const float* bq    = (const float*)d_in[2];
    const float* Wk    = (const float*)d_in[3];
    const float* bk    = (const float*)d_in[4];
    const float* Wv    = (const float*)d_in[5];
    const float* bv    = (const float*)d_in[6];
    const float* gamma = (const float*)d_in[7];
    float* out = (float*)d_out;
    float* ws  = (float*)d_ws;

    float* Q  = ws + WS_Q;
    float* K  = ws + WS_K;
    float* V  = ws + WS_V;
    float* Mx = ws + WS_MX;
    float* Ri = ws + WS_RI;
    float* Mp = ws + WS_MP;
    float* Dp = ws + WS_DP;

    qkv_kernel<<<dim3(36, 2), 256, 0, stream>>>(x, Wq, bq, Wk, bk, Wv, bv, Q, K, V);
    md_kernel<<<dim3(36, 2, 8), 256, 0, stream>>>(Q, K, Mp, Dp);
    merge_kernel<<<dim3(72), 256, 0, stream>>>(Mp, Dp, Mx, Ri);
    init_kernel<<<dim3(1152), 256, 0, stream>>>(x, out);
    pv_kernel<<<dim3(144, 2, 4), 256, 0, stream>>>(Q, K, V, Mx, Ri, gamma, out);
}

// Round 2
// 242.643 us; speedup vs baseline: 2.4516x; 2.4516x over previous
//
#include <hip/hip_runtime.h>
#include <math.h>

#define NN 9216           // 96*96

typedef __attribute__((ext_vector_type(8))) __bf16 bf16x8;
typedef __attribute__((ext_vector_type(4))) float f32x4;

#define MFMA16(a,b,c) __builtin_amdgcn_mfma_f32_16x16x32_bf16(a,b,c,0,0,0)

__device__ __forceinline__ bf16x8 zero8() {
    bf16x8 z;
    #pragma unroll
    for (int i = 0; i < 8; i++) z[i] = (__bf16)0.0f;
    return z;
}

__device__ __forceinline__ unsigned int pk2(float a, float b) {
    unsigned short ua = __builtin_bit_cast(unsigned short, (__bf16)a);
    unsigned short ub = __builtin_bit_cast(unsigned short, (__bf16)b);
    return (unsigned int)ua | ((unsigned int)ub << 16);
}

// Workspace layout (bytes):
//   QB : 0        [B][N][8]  bf16
//   KB : 294912   [B][N][8]  bf16
//   VB : 589824   [B][64][N] bf16  (folded in place by stats kernel)
#define OFF_QB 0
#define OFF_KB 294912
#define OFF_VB 589824

// ---------------- Kernel 1: QKV projections (bf16 outputs) ----------------
// grid (36, 2), block 256. Thread owns one spatial position n.
__global__ __launch_bounds__(256) void qkv_kernel(
    const float* __restrict__ x,
    const float* __restrict__ Wq, const float* __restrict__ bq,
    const float* __restrict__ Wk, const float* __restrict__ bk,
    const float* __restrict__ Wv, const float* __restrict__ bv,
    __bf16* __restrict__ QB, __bf16* __restrict__ KB, __bf16* __restrict__ VB)
{
    __shared__ float wq[512], wk[512], wv[4096], bqs[8], bks[8], bvs[64];
    int tid = threadIdx.x;
    for (int i = tid; i < 512; i += 256) { wq[i] = Wq[i]; wk[i] = Wk[i]; }
    for (int i = tid; i < 4096; i += 256) wv[i] = Wv[i];
    if (tid < 8)  { bqs[tid] = bq[tid]; bks[tid] = bk[tid]; }
    if (tid < 64) bvs[tid] = bv[tid];
    __syncthreads();

    int b = blockIdx.y;
    int n = blockIdx.x * 256 + tid;

    float xc[64];
    #pragma unroll
    for (int c = 0; c < 64; c++) xc[c] = x[((size_t)(b*64 + c))*NN + n];

    float q[8], k[8];
    #pragma unroll
    for (int o = 0; o < 8; o++) { q[o] = bqs[o]; k[o] = bks[o]; }
    #pragma unroll
    for (int c = 0; c < 64; c++) {
        float xv = xc[c];
        #pragma unroll
        for (int o = 0; o < 8; o++) {
            q[o] = fmaf(wq[o*64+c], xv, q[o]);
            k[o] = fmaf(wk[o*64+c], xv, k[o]);
        }
    }
    bf16x8 qv, kv;
    #pragma unroll
    for (int o = 0; o < 8; o++) { qv[o] = (__bf16)q[o]; kv[o] = (__bf16)k[o]; }
    *(bf16x8*)(QB + ((size_t)(b*NN) + n)*8) = qv;
    *(bf16x8*)(KB + ((size_t)(b*NN) + n)*8) = kv;

    float v[64];
    #pragma unroll
    for (int o = 0; o < 64; o++) v[o] = bvs[o];
    #pragma unroll
    for (int c = 0; c < 64; c++) {
        float xv = xc[c];
        #pragma unroll
        for (int o = 0; o < 64; o++) v[o] = fmaf(wv[o*64+c], xv, v[o]);
    }
    #pragma unroll
    for (int o = 0; o < 64; o++)
        VB[((size_t)(b*64 + o))*NN + n] = (__bf16)v[o];
}

// ---------------- Kernel 2: D[n] = sum_m exp(E[m,n]) via MFMA; fold V ----------------
// grid (144, 2), block 256. Block owns 64 key columns n; wave w owns 16 of them.
// E^T[n,m] = K[n] . Q[m] computed as MFMA(A=K rows, B=Q cols), K-dim 8 padded to 32.
__global__ __launch_bounds__(256) void stats_fold_kernel(
    const __bf16* __restrict__ QB, const __bf16* __restrict__ KB,
    const float* __restrict__ gamma_p, __bf16* __restrict__ VB)
{
    __shared__ float Rl[64];
    int tid = threadIdx.x;
    int lane = tid & 63, w = tid >> 6;
    int l15 = lane & 15, G = lane >> 4;
    int b = blockIdx.y;
    int nb = blockIdx.x * 64;

    bf16x8 kf = zero8();
    if (lane < 16)
        kf = *(const bf16x8*)(KB + ((size_t)(b*NN) + nb + w*16 + l15)*8);

    float D0 = 0.f, D1 = 0.f, D2 = 0.f, D3 = 0.f;
    const __bf16* Qb = QB + (size_t)b*NN*8;

    for (int m0 = 0; m0 < NN; m0 += 128) {
        bf16x8 qf[8];
        #pragma unroll
        for (int u = 0; u < 8; u++) {
            qf[u] = zero8();
            if (lane < 16)
                qf[u] = *(const bf16x8*)(Qb + (size_t)(m0 + u*16 + l15)*8);
        }
        f32x4 c[8];
        #pragma unroll
        for (int u = 0; u < 8; u++) {
            f32x4 z = {0.f, 0.f, 0.f, 0.f};
            c[u] = MFMA16(kf, qf[u], z);
        }
        #pragma unroll
        for (int u = 0; u < 8; u++) {
            D0 += __expf(c[u][0]); D1 += __expf(c[u][1]);
            D2 += __expf(c[u][2]); D3 += __expf(c[u][3]);
        }
    }
    // reduce over the 16 m-columns (lanes sharing G)
    #pragma unroll
    for (int off = 1; off < 16; off <<= 1) {
        D0 += __shfl_xor(D0, off);
        D1 += __shfl_xor(D1, off);
        D2 += __shfl_xor(D2, off);
        D3 += __shfl_xor(D3, off);
    }
    float gamma = gamma_p[0];
    if (l15 == 0) {
        Rl[w*16 + G*4 + 0] = gamma / D0;
        Rl[w*16 + G*4 + 1] = gamma / D1;
        Rl[w*16 + G*4 + 2] = gamma / D2;
        Rl[w*16 + G*4 + 3] = gamma / D3;
    }
    __syncthreads();

    // fold: V''[c,n] = gamma * V[c,n] / D[n]  (in place, bf16)
    int n = tid & 63;
    int c0 = tid >> 6;
    float r = Rl[n];
    #pragma unroll
    for (int cc = 0; cc < 16; cc++) {
        int c = cc*4 + c0;
        size_t idx = ((size_t)(b*64 + c))*NN + nb + n;
        VB[idx] = (__bf16)((float)VB[idx] * r);
    }
}

// ---------------- Kernel 3: out = x ----------------
__global__ __launch_bounds__(256) void init_kernel(
    const float* __restrict__ x, float* __restrict__ out)
{
    int i = blockIdx.x*256 + threadIdx.x;
    ((float4*)out)[i] = ((const float4*)x)[i];
}

// ---------------- Kernel 4: fused exp(E) + PV via MFMA ----------------
// grid (72, 2, 8), block 256 (4 waves). Block: 128 m's; wave: 32 m's (2 m16 frags).
// n-split 8: each block covers 1152 n's in 18 stages of 64. atomicAdd epilogue.
__global__ __launch_bounds__(256) void pv_kernel(
    const __bf16* __restrict__ QB, const __bf16* __restrict__ KB,
    const __bf16* __restrict__ VB, float* __restrict__ out)
{
    __shared__ __bf16 klin[64*8];      // 1KB  [n][8] linear
    __shared__ __bf16 vbuf[64*64];     // 8KB  [c][n] XOR-swizzled
    __shared__ __bf16 pbuf[4][32*64];  // 16KB per-wave [m32][n64] XOR-swizzled

    int tid = threadIdx.x;
    int lane = tid & 63, w = tid >> 6;
    int l15 = lane & 15, G = lane >> 4;
    int b = blockIdx.y, s = blockIdx.z;
    int mw = blockIdx.x * 128 + w * 32;

    bf16x8 qfA = zero8(), qfB = zero8();
    if (lane < 16) {
        qfA = *(const bf16x8*)(QB + ((size_t)(b*NN) + mw + l15)*8);
        qfB = *(const bf16x8*)(QB + ((size_t)(b*NN) + mw + 16 + l15)*8);
    }

    f32x4 acc[2][4];
    #pragma unroll
    for (int i = 0; i < 2; i++)
        #pragma unroll
        for (int j = 0; j < 4; j++) {
            f32x4 z = {0.f, 0.f, 0.f, 0.f};
            acc[i][j] = z;
        }

    char* pb = (char*)pbuf[w];
    int swzA = (l15 & 7) << 4;   // pbuf row swizzle for rows l15 and l15+16 (same &7)

    for (int st = 0; st < 18; st++) {
        int n0 = s*1152 + st*64;
        __syncthreads();
        // stage K: 1KB contiguous
        if (tid < 64)
            *(float4*)(klin + tid*8) =
                *(const float4*)(KB + ((size_t)(b*NN) + n0 + tid)*8);
        // stage V'': 64c x 64n bf16, swizzled [c][n]
        #pragma unroll
        for (int i = 0; i < 2; i++) {
            int p = tid + i*256;
            int c = p >> 3, ch = p & 7;
            float4 v = *(const float4*)(VB + ((size_t)(b*64 + c))*NN + n0 + ch*8);
            *(float4*)((char*)vbuf + c*128 + ((ch*16) ^ ((c & 7) << 4))) = v;
        }
        __syncthreads();

        // E^T tiles: 4 n16-tiles, both m16 frags; exp; pack to pbuf
        #pragma unroll
        for (int ti = 0; ti < 4; ti++) {
            bf16x8 kfr = zero8();
            if (lane < 16)
                kfr = *(const bf16x8*)(klin + (ti*16 + l15)*8);
            f32x4 z = {0.f, 0.f, 0.f, 0.f};
            f32x4 cA = MFMA16(kfr, qfA, z);
            f32x4 cB = MFMA16(kfr, qfB, z);
            uint2 wA, wB;
            wA.x = pk2(__expf(cA[0]), __expf(cA[1]));
            wA.y = pk2(__expf(cA[2]), __expf(cA[3]));
            wB.x = pk2(__expf(cB[0]), __expf(cB[1]));
            wB.y = pk2(__expf(cB[2]), __expf(cB[3]));
            int colb = ti*32 + 8*G;              // byte offset of n within row
            *(uint2*)(pb + l15*128        + (colb ^ swzA)) = wA;
            *(uint2*)(pb + (l15+16)*128   + (colb ^ swzA)) = wB;
        }

        // PV: out[m,c] += P[m,n] * V''[n,c], 2 k-steps of 32 n
        #pragma unroll
        for (int ks = 0; ks < 2; ks++) {
            int nbyte = ks*64 + 16*G;
            bf16x8 aA = *(bf16x8*)(pb + l15*128      + (nbyte ^ swzA));
            bf16x8 aB = *(bf16x8*)(pb + (l15+16)*128 + (nbyte ^ swzA));
            #pragma unroll
            for (int ct = 0; ct < 4; ct++) {
                int c = ct*16 + l15;
                bf16x8 bfr = *(bf16x8*)((char*)vbuf + c*128 + (nbyte ^ ((c & 7) << 4)));
                acc[0][ct] = MFMA16(aA, bfr, acc[0][ct]);
                acc[1][ct] = MFMA16(aB, bfr, acc[1][ct]);
            }
        }
    }

    // epilogue: out[c][m] += acc (gamma already folded into V'')
    #pragma unroll
    for (int mh = 0; mh < 2; mh++)
        #pragma unroll
        for (int ct = 0; ct < 4; ct++)
            #pragma unroll
            for (int r = 0; r < 4; r++) {
                int m = mw + mh*16 + G*4 + r;
                int c = ct*16 + l15;
                atomicAdd(out + ((size_t)(b*64 + c))*NN + m, acc[mh][ct][r]);
            }
}

extern "C" void kernel_launch(void* const* d_in, const int* in_sizes, int n_in,
                              void* d_out, int out_size, void* d_ws, size_t ws_size,
                              hipStream_t stream) {
    const float* x     = (const float*)d_in[0];
    const float* Wq    = (const float*)d_in[1];
    const float* bq    = (const float*)d_in[2];
    const float* Wk    = (const float*)d_in[3];
    const float* bk    = (const float*)d_in[4];
    const float* Wv    = (const float*)d_in[5];
    const float* bv    = (const float*)d_in[6];
    const float* gamma = (const float*)d_in[7];
    float* out = (float*)d_out;
    char* ws   = (char*)d_ws;

    __bf16* QB = (__bf16*)(ws + OFF_QB);
    __bf16* KB = (__bf16*)(ws + OFF_KB);
    __bf16* VB = (__bf16*)(ws + OFF_VB);

    qkv_kernel<<<dim3(36, 2), 256, 0, stream>>>(x, Wq, bq, Wk, bk, Wv, bv, QB, KB, VB);
    stats_fold_kernel<<<dim3(144, 2), 256, 0, stream>>>(QB, KB, gamma, VB);
    init_kernel<<<dim3(1152), 256, 0, stream>>>(x, out);
    pv_kernel<<<dim3(72, 2, 8), 256, 0, stream>>>(QB, KB, VB, out);
}

// Round 3
// 133.446 us; speedup vs baseline: 4.4577x; 1.8183x over previous
//
#include <hip/hip_runtime.h>
#include <math.h>

#define NN 9216           // 96*96

typedef __attribute__((ext_vector_type(8))) __bf16 bf16x8;
typedef __attribute__((ext_vector_type(4))) float f32x4;
typedef __attribute__((ext_vector_type(16))) float f32x16;
typedef __attribute__((ext_vector_type(4))) unsigned int u32x4;

#define MFMA32(a,b,c) __builtin_amdgcn_mfma_f32_32x32x16_bf16(a,b,c,0,0,0)

__device__ __forceinline__ bf16x8 zero8() {
    bf16x8 z;
    #pragma unroll
    for (int i = 0; i < 8; i++) z[i] = (__bf16)0.0f;
    return z;
}

__device__ __forceinline__ unsigned int pk2(float a, float b) {
    unsigned short ua = __builtin_bit_cast(unsigned short, (__bf16)a);
    unsigned short ub = __builtin_bit_cast(unsigned short, (__bf16)b);
    return (unsigned int)ua | ((unsigned int)ub << 16);
}

__device__ __forceinline__ void plane_swap(unsigned int &a, unsigned int &b) {
    asm("v_permlane32_swap_b32 %0, %1" : "+v"(a), "+v"(b));
}

__device__ __forceinline__ void cp16(void* lds, const void* g) {
    __builtin_amdgcn_global_load_lds(
        (const __attribute__((address_space(1))) unsigned int*)g,
        (__attribute__((address_space(3))) unsigned int*)lds, 16, 0, 0);
}

// Workspace layout (bytes):
#define OFF_QB 0              // [B][N][8]  bf16
#define OFF_KB 294912         // [B][N][8]  bf16
#define OFF_VB 589824         // [B][64][N] bf16 (folded in place by stats)
#define OFF_PARTS 2949120     // [8][B][64][N] fp32 partials
#define WS_NEED 40697856ULL

// ---------------- Kernel 1: QKV projections ----------------
// grid (36, 2, 4), block 256. z = V-output quarter; z==0 also does Q,K.
__global__ __launch_bounds__(256) void qkv_kernel(
    const float* __restrict__ x,
    const float* __restrict__ Wq, const float* __restrict__ bq,
    const float* __restrict__ Wk, const float* __restrict__ bk,
    const float* __restrict__ Wv, const float* __restrict__ bv,
    __bf16* __restrict__ QB, __bf16* __restrict__ KB, __bf16* __restrict__ VB)
{
    __shared__ float wvs[1024], wqs[512], wks[512], bvs[16], bqs[8], bks[8];
    int tid = threadIdx.x;
    int z = blockIdx.z, b = blockIdx.y;
    for (int i = tid; i < 1024; i += 256) wvs[i] = Wv[z*1024 + i];
    if (z == 0)
        for (int i = tid; i < 512; i += 256) { wqs[i] = Wq[i]; wks[i] = Wk[i]; }
    if (tid < 16) bvs[tid] = bv[z*16 + tid];
    if (tid < 8)  { bqs[tid] = bq[tid]; bks[tid] = bk[tid]; }
    __syncthreads();

    int n = blockIdx.x * 256 + tid;

    float xc[64];
    #pragma unroll
    for (int c = 0; c < 64; c++) xc[c] = x[((size_t)(b*64 + c))*NN + n];

    float v[16];
    #pragma unroll
    for (int o = 0; o < 16; o++) v[o] = bvs[o];
    #pragma unroll
    for (int c = 0; c < 64; c++) {
        float xv = xc[c];
        #pragma unroll
        for (int o = 0; o < 16; o++) v[o] = fmaf(wvs[o*64+c], xv, v[o]);
    }
    #pragma unroll
    for (int o = 0; o < 16; o++)
        VB[((size_t)(b*64 + z*16 + o))*NN + n] = (__bf16)v[o];

    if (z == 0) {
        float q[8], k[8];
        #pragma unroll
        for (int o = 0; o < 8; o++) { q[o] = bqs[o]; k[o] = bks[o]; }
        #pragma unroll
        for (int c = 0; c < 64; c++) {
            float xv = xc[c];
            #pragma unroll
            for (int o = 0; o < 8; o++) {
                q[o] = fmaf(wqs[o*64+c], xv, q[o]);
                k[o] = fmaf(wks[o*64+c], xv, k[o]);
            }
        }
        bf16x8 qv, kv;
        #pragma unroll
        for (int o = 0; o < 8; o++) { qv[o] = (__bf16)q[o]; kv[o] = (__bf16)k[o]; }
        *(bf16x8*)(QB + ((size_t)b*NN + n)*8) = qv;
        *(bf16x8*)(KB + ((size_t)b*NN + n)*8) = kv;
    }
}

// ---------------- Kernel 2: D[n] via 32x32x16 MFMA; fold V ----------------
// grid (288, 2), block 256 (4 waves). Block owns 32 n; waves split m 4-ways.
__global__ __launch_bounds__(256) void stats_fold_kernel(
    const __bf16* __restrict__ QB, const __bf16* __restrict__ KB,
    const float* __restrict__ gamma_p, __bf16* __restrict__ VB)
{
    __shared__ float Dl[4][32];
    __shared__ float Rl[32];
    int tid = threadIdx.x;
    int lane = tid & 63, w = tid >> 6;
    int l31 = lane & 31, h = lane >> 5;
    int b = blockIdx.y;
    int n0 = blockIdx.x * 32;

    f32x16 Z16;
    #pragma unroll
    for (int r = 0; r < 16; r++) Z16[r] = 0.0f;

    bf16x8 kf = zero8();
    if (lane < 32)
        kf = *(const bf16x8*)(KB + ((size_t)b*NN + n0 + l31)*8);

    float Dacc[16];
    #pragma unroll
    for (int r = 0; r < 16; r++) Dacc[r] = 0.0f;

    const __bf16* Qb = QB + (size_t)b*NN*8;
    for (int it = 0; it < 72; it++) {
        int m = w*2304 + it*32;
        bf16x8 qf = zero8();
        if (lane < 32)
            qf = *(const bf16x8*)(Qb + (size_t)(m + l31)*8);
        f32x16 e = MFMA32(kf, qf, Z16);
        #pragma unroll
        for (int r = 0; r < 16; r++) Dacc[r] += __expf(e[r]);
    }
    #pragma unroll
    for (int r = 0; r < 16; r++) {
        #pragma unroll
        for (int mask = 1; mask < 32; mask <<= 1)
            Dacc[r] += __shfl_xor(Dacc[r], mask);
    }
    if (l31 == 0) {
        #pragma unroll
        for (int r = 0; r < 16; r++)
            Dl[w][(r&3) + 8*(r>>2) + 4*h] = Dacc[r];
    }
    __syncthreads();
    if (tid < 32)
        Rl[tid] = gamma_p[0] / (Dl[0][tid] + Dl[1][tid] + Dl[2][tid] + Dl[3][tid]);
    __syncthreads();

    // fold: V''[c,n] = gamma * V[c,n] / D[n]
    int c = tid >> 2, j = tid & 3;
    __bf16* ptr = VB + ((size_t)(b*64 + c))*NN + n0 + j*8;
    bf16x8 vv = *(bf16x8*)ptr;
    #pragma unroll
    for (int i = 0; i < 8; i++)
        vv[i] = (__bf16)((float)vv[i] * Rl[j*8 + i]);
    *(bf16x8*)ptr = vv;
}

// ---------------- Kernel 3: out = x (atomic-fallback path only) ----------------
__global__ __launch_bounds__(256) void init_kernel(
    const float* __restrict__ x, float* __restrict__ out)
{
    int i = blockIdx.x*256 + threadIdx.x;
    ((float4*)out)[i] = ((const float4*)x)[i];
}

// ---------------- Kernel 4: fused exp(E) + PV, all 32x32x16, P in registers ----------------
// grid (36, 2, 8), block 256 (4 waves). Block: 256 m; wave: 64 m. Split z: 1152 n, 18 stages of 64.
__global__ __launch_bounds__(256) void pv_kernel(
    const __bf16* __restrict__ QB, const __bf16* __restrict__ KB,
    const __bf16* __restrict__ VB, float* __restrict__ out,
    float* __restrict__ parts)
{
    __shared__ __bf16 klin[2][64*8];     // 2 x 1KB
    __shared__ __bf16 vbuf[2][64*64];    // 2 x 8KB, [c][n] XOR-swizzled

    int tid = threadIdx.x;
    int lane = tid & 63, w = tid >> 6;
    int l31 = lane & 31, h = lane >> 5;
    int b = blockIdx.y, s = blockIdx.z;
    int mw = blockIdx.x * 256 + w * 64;

    f32x16 Z16;
    #pragma unroll
    for (int r = 0; r < 16; r++) Z16[r] = 0.0f;

    bf16x8 qf0 = zero8(), qf1 = zero8();
    if (lane < 32) {
        qf0 = *(const bf16x8*)(QB + ((size_t)b*NN + mw + l31)*8);
        qf1 = *(const bf16x8*)(QB + ((size_t)b*NN + mw + 32 + l31)*8);
    }

    f32x16 acc[2][2];
    #pragma unroll
    for (int i = 0; i < 2; i++)
        #pragma unroll
        for (int j = 0; j < 2; j++) acc[i][j] = Z16;

#define STAGE(bi, stq) do {                                                   \
    int n0_ = s*1152 + (stq)*64;                                              \
    _Pragma("unroll")                                                         \
    for (int i_ = 0; i_ < 2; i_++) {                                          \
        int p2_ = tid + i_*256;                                               \
        int c_ = p2_ >> 3, h7_ = p2_ & 7;                                     \
        int xc_ = h7_ ^ (c_ & 7);                                             \
        cp16((char*)vbuf[bi] + i_*4096 + w*1024,                              \
             VB + ((size_t)(b*64 + c_))*NN + n0_ + xc_*8);                    \
    }                                                                         \
    if (w == 0)                                                               \
        cp16((char*)klin[bi], KB + ((size_t)b*NN + n0_ + lane)*8);            \
} while (0)

    STAGE(0, 0);

    for (int st = 0; st < 18; st++) {
        int bi = st & 1;
        __syncthreads();
        if (st < 17) {
            if (bi == 0) STAGE(1, st+1); else STAGE(0, st+1);
        }
        const __bf16* kl = klin[bi];
        char* vb = (char*)vbuf[bi];

        #pragma unroll
        for (int nt = 0; nt < 2; nt++) {
            bf16x8 kfr = zero8();
            if (lane < 32)
                kfr = *(const bf16x8*)(kl + (nt*32 + l31)*8);

            bf16x8 pa[2][2];
            #pragma unroll
            for (int mt = 0; mt < 2; mt++) {
                f32x16 e = MFMA32(kfr, mt ? qf1 : qf0, Z16);
                float pf[16];
                #pragma unroll
                for (int r = 0; r < 16; r++) pf[r] = __expf(e[r]);
                unsigned int u[8];
                #pragma unroll
                for (int q = 0; q < 8; q++) u[q] = pk2(pf[2*q], pf[2*q+1]);
                plane_swap(u[0], u[2]); plane_swap(u[1], u[3]);
                plane_swap(u[4], u[6]); plane_swap(u[5], u[7]);
                u32x4 t0 = {u[0], u[1], u[2], u[3]};
                u32x4 t1 = {u[4], u[5], u[6], u[7]};
                pa[mt][0] = __builtin_bit_cast(bf16x8, t0);
                pa[mt][1] = __builtin_bit_cast(bf16x8, t1);
            }
            #pragma unroll
            for (int ks = 0; ks < 2; ks++) {
                #pragma unroll
                for (int ct = 0; ct < 2; ct++) {
                    int c = ct*32 + l31;
                    bf16x8 bfr = *(const bf16x8*)(vb + c*128 +
                        ((nt*64 + ks*32 + h*16) ^ ((c & 7) << 4)));
                    acc[0][ct] = MFMA32(pa[0][ks], bfr, acc[0][ct]);
                    acc[1][ct] = MFMA32(pa[1][ks], bfr, acc[1][ct]);
                }
            }
        }
    }

    if (parts != nullptr) {
        float* pp = parts + ((size_t)(s*2 + b))*64*NN;
        #pragma unroll
        for (int mt = 0; mt < 2; mt++)
            #pragma unroll
            for (int ct = 0; ct < 2; ct++) {
                int c = ct*32 + l31;
                float* row = pp + (size_t)c*NN + mw + mt*32 + h*4;
                #pragma unroll
                for (int q = 0; q < 4; q++) {
                    float4 v4 = make_float4(acc[mt][ct][4*q],   acc[mt][ct][4*q+1],
                                            acc[mt][ct][4*q+2], acc[mt][ct][4*q+3]);
                    *(float4*)(row + q*8) = v4;
                }
            }
    } else {
        #pragma unroll
        for (int mt = 0; mt < 2; mt++)
            #pragma unroll
            for (int ct = 0; ct < 2; ct++) {
                int c = ct*32 + l31;
                #pragma unroll
                for (int r = 0; r < 16; r++) {
                    int m = mw + mt*32 + (r&3) + 8*(r>>2) + 4*h;
                    atomicAdd(out + ((size_t)(b*64 + c))*NN + m, acc[mt][ct][r]);
                }
            }
    }
}

// ---------------- Kernel 5: out = x + sum_s parts[s] ----------------
__global__ __launch_bounds__(256) void reduce_kernel(
    const float* __restrict__ x, const float* __restrict__ parts,
    float* __restrict__ out)
{
    int i = blockIdx.x*256 + threadIdx.x;   // over 294912 float4
    float4 o = ((const float4*)x)[i];
    #pragma unroll
    for (int sIdx = 0; sIdx < 8; sIdx++) {
        float4 p = ((const float4*)parts)[(size_t)sIdx*294912 + i];
        o.x += p.x; o.y += p.y; o.z += p.z; o.w += p.w;
    }
    ((float4*)out)[i] = o;
}

extern "C" void kernel_launch(void* const* d_in, const int* in_sizes, int n_in,
                              void* d_out, int out_size, void* d_ws, size_t ws_size,
                              hipStream_t stream) {
    const float* x     = (const float*)d_in[0];
    const float* Wq    = (const float*)d_in[1];
    const float* bq    = (const float*)d_in[2];
    const float* Wk    = (const float*)d_in[3];
    const float* bk    = (const float*)d_in[4];
    const float* Wv    = (const float*)d_in[5];
    const float* bv    = (const float*)d_in[6];
    const float* gamma = (const float*)d_in[7];
    float* out = (float*)d_out;
    char* ws   = (char*)d_ws;

    __bf16* QB = (__bf16*)(ws + OFF_QB);
    __bf16* KB = (__bf16*)(ws + OFF_KB);
    __bf16* VB = (__bf16*)(ws + OFF_VB);

    qkv_kernel<<<dim3(36, 2, 4), 256, 0, stream>>>(x, Wq, bq, Wk, bk, Wv, bv, QB, KB, VB);
    stats_fold_kernel<<<dim3(288, 2), 256, 0, stream>>>(QB, KB, gamma, VB);

    if (ws_size >= WS_NEED) {
        float* parts = (float*)(ws + OFF_PARTS);
        pv_kernel<<<dim3(36, 2, 8), 256, 0, stream>>>(QB, KB, VB, out, parts);
        reduce_kernel<<<dim3(1152), 256, 0, stream>>>(x, parts, out);
    } else {
        init_kernel<<<dim3(1152), 256, 0, stream>>>(x, out);
        pv_kernel<<<dim3(36, 2, 8), 256, 0, stream>>>(QB, KB, VB, out, nullptr);
    }
}

// Round 5
// 106.309 us; speedup vs baseline: 5.5956x; 1.2553x over previous
//
#include <hip/hip_runtime.h>
#include <math.h>

#define NN 9216           // 96*96
#define LOG2E 1.4426950408889634f

typedef __attribute__((ext_vector_type(8))) __bf16 bf16x8;
typedef __attribute__((ext_vector_type(16))) float f32x16;
typedef __attribute__((ext_vector_type(4))) unsigned int u32x4;

#define MFMA32(a,b,c) __builtin_amdgcn_mfma_f32_32x32x16_bf16(a,b,c,0,0,0)

#if __has_builtin(__builtin_amdgcn_exp2f)
#define EXP2(x) __builtin_amdgcn_exp2f(x)
#else
#define EXP2(x) exp2f(x)
#endif

__device__ __forceinline__ bf16x8 zero8() {
    bf16x8 z;
    #pragma unroll
    for (int i = 0; i < 8; i++) z[i] = (__bf16)0.0f;
    return z;
}

__device__ __forceinline__ unsigned int pk2(float a, float b) {
    unsigned short ua = __builtin_bit_cast(unsigned short, (__bf16)a);
    unsigned short ub = __builtin_bit_cast(unsigned short, (__bf16)b);
    return (unsigned int)ua | ((unsigned int)ub << 16);
}

__device__ __forceinline__ void plane_swap(unsigned int &a, unsigned int &b) {
    asm("v_permlane32_swap_b32 %0, %1" : "+v"(a), "+v"(b));
}

__device__ __forceinline__ void cp16(void* lds, const void* g) {
    __builtin_amdgcn_global_load_lds(
        (const __attribute__((address_space(1))) unsigned int*)g,
        (__attribute__((address_space(3))) unsigned int*)lds, 16, 0, 0);
}

// Workspace layout (bytes):
#define OFF_QB 0              // [B][N][8]  bf16 (Q pre-scaled by log2e)
#define OFF_KB 294912         // [B][N][8]  bf16
#define OFF_VB 589824         // [B][64][N] bf16 (folded in place)
#define OFF_DP 2949120        // [2][B][N]  fp32 D-partials
#define OFF_PARTS 3096576     // [8][B][64][N] bf16 PV partials
#define WS_NEED 21970944ULL

// ---------------- Kernel 1: QKV projections ----------------
// grid (36, 2, 4), block 256. z = V-output quarter; z==0 also does Q,K.
__global__ __launch_bounds__(256) void qkv_kernel(
    const float* __restrict__ x,
    const float* __restrict__ Wq, const float* __restrict__ bq,
    const float* __restrict__ Wk, const float* __restrict__ bk,
    const float* __restrict__ Wv, const float* __restrict__ bv,
    __bf16* __restrict__ QB, __bf16* __restrict__ KB, __bf16* __restrict__ VB)
{
    __shared__ float wvs[1024], wqs[512], wks[512], bvs[16], bqs[8], bks[8];
    int tid = threadIdx.x;
    int z = blockIdx.z, b = blockIdx.y;
    for (int i = tid; i < 1024; i += 256) wvs[i] = Wv[z*1024 + i];
    if (z == 0)
        for (int i = tid; i < 512; i += 256) { wqs[i] = Wq[i]; wks[i] = Wk[i]; }
    if (tid < 16) bvs[tid] = bv[z*16 + tid];
    if (tid < 8)  { bqs[tid] = bq[tid]; bks[tid] = bk[tid]; }
    __syncthreads();

    int n = blockIdx.x * 256 + tid;

    float xc[64];
    #pragma unroll
    for (int c = 0; c < 64; c++) xc[c] = x[((size_t)(b*64 + c))*NN + n];

    float v[16];
    #pragma unroll
    for (int o = 0; o < 16; o++) v[o] = bvs[o];
    #pragma unroll
    for (int c = 0; c < 64; c++) {
        float xv = xc[c];
        #pragma unroll
        for (int o = 0; o < 16; o++) v[o] = fmaf(wvs[o*64+c], xv, v[o]);
    }
    #pragma unroll
    for (int o = 0; o < 16; o++)
        VB[((size_t)(b*64 + z*16 + o))*NN + n] = (__bf16)v[o];

    if (z == 0) {
        float q[8], k[8];
        #pragma unroll
        for (int o = 0; o < 8; o++) { q[o] = bqs[o]; k[o] = bks[o]; }
        #pragma unroll
        for (int c = 0; c < 64; c++) {
            float xv = xc[c];
            #pragma unroll
            for (int o = 0; o < 8; o++) {
                q[o] = fmaf(wqs[o*64+c], xv, q[o]);
                k[o] = fmaf(wks[o*64+c], xv, k[o]);
            }
        }
        bf16x8 qv, kv;
        #pragma unroll
        for (int o = 0; o < 8; o++) {
            qv[o] = (__bf16)(q[o] * LOG2E);   // fold log2e: exp(E)=exp2(E')
            kv[o] = (__bf16)k[o];
        }
        *(bf16x8*)(QB + ((size_t)b*NN + n)*8) = qv;
        *(bf16x8*)(KB + ((size_t)b*NN + n)*8) = kv;
    }
}

// ---------------- Kernel 2: D-partials via 32x32x16 MFMA ----------------
// grid (288, 2, 2), block 256 (4 waves). Block owns 32 n; z+wave split m 8 ways.
__global__ __launch_bounds__(256) void stats_kernel(
    const __bf16* __restrict__ QB, const __bf16* __restrict__ KB,
    float* __restrict__ Dp)
{
    __shared__ float Dl[4][32];
    int tid = threadIdx.x;
    int lane = tid & 63, w = tid >> 6;
    int l31 = lane & 31, h = lane >> 5;
    int b = blockIdx.y, z = blockIdx.z;
    int n0 = blockIdx.x * 32;

    f32x16 Z16;
    #pragma unroll
    for (int r = 0; r < 16; r++) Z16[r] = 0.0f;

    bf16x8 kf = zero8();
    if (lane < 32)
        kf = *(const bf16x8*)(KB + ((size_t)b*NN + n0 + l31)*8);

    float Dacc[16];
    #pragma unroll
    for (int r = 0; r < 16; r++) Dacc[r] = 0.0f;

    const __bf16* Qb = QB + (size_t)b*NN*8;
    int mbase = z*4608 + w*1152;
    for (int it = 0; it < 36; it++) {
        bf16x8 qf = zero8();
        if (lane < 32)
            qf = *(const bf16x8*)(Qb + (size_t)(mbase + it*32 + l31)*8);
        f32x16 e = MFMA32(kf, qf, Z16);
        #pragma unroll
        for (int r = 0; r < 16; r++) Dacc[r] += EXP2(e[r]);
    }
    #pragma unroll
    for (int r = 0; r < 16; r++) {
        #pragma unroll
        for (int mask = 1; mask < 32; mask <<= 1)
            Dacc[r] += __shfl_xor(Dacc[r], mask);
    }
    if (l31 == 0) {
        #pragma unroll
        for (int r = 0; r < 16; r++)
            Dl[w][(r&3) + 8*(r>>2) + 4*h] = Dacc[r];
    }
    __syncthreads();
    if (tid < 32)
        Dp[((size_t)z*2 + b)*NN + n0 + tid] =
            Dl[0][tid] + Dl[1][tid] + Dl[2][tid] + Dl[3][tid];
}

// ---------------- Kernel 3: R = gamma/D; fold into V ----------------
// grid (288, 2), block 256.
__global__ __launch_bounds__(256) void fold_kernel(
    const float* __restrict__ Dp, const float* __restrict__ gamma_p,
    __bf16* __restrict__ VB)
{
    __shared__ float Rl[32];
    int tid = threadIdx.x;
    int b = blockIdx.y;
    int n0 = blockIdx.x * 32;
    if (tid < 32)
        Rl[tid] = gamma_p[0] / (Dp[(size_t)b*NN + n0 + tid] +
                                Dp[((size_t)2 + b)*NN + n0 + tid]);
    __syncthreads();

    int c = tid >> 2, j = tid & 3;
    __bf16* ptr = VB + ((size_t)(b*64 + c))*NN + n0 + j*8;
    bf16x8 vv = *(bf16x8*)ptr;
    #pragma unroll
    for (int i = 0; i < 8; i++)
        vv[i] = (__bf16)((float)vv[i] * Rl[j*8 + i]);
    *(bf16x8*)ptr = vv;
}

// ---------------- Kernel 4: out = x (atomic-fallback path only) ----------------
__global__ __launch_bounds__(256) void init_kernel(
    const float* __restrict__ x, float* __restrict__ out)
{
    int i = blockIdx.x*256 + threadIdx.x;
    ((float4*)out)[i] = ((const float4*)x)[i];
}

// ---------------- Kernel 5: fused exp2(E') + PV ----------------
// grid (72, 2, 8), block 256 (4 waves). Block: 128 m; wave: 32 m.
// Split z: 1152 n, 18 stages of 64. bf16 partial stores.
__global__ __launch_bounds__(256) void pv_kernel(
    const __bf16* __restrict__ QB, const __bf16* __restrict__ KB,
    const __bf16* __restrict__ VB, float* __restrict__ out,
    __bf16* __restrict__ parts)
{
    __shared__ __bf16 klin[2][64*8];     // 2 x 1KB
    __shared__ __bf16 vbuf[2][64*64];    // 2 x 8KB, [c][n] XOR-swizzled

    int tid = threadIdx.x;
    int lane = tid & 63, w = tid >> 6;
    int l31 = lane & 31, h = lane >> 5;
    int b = blockIdx.y, s = blockIdx.z;
    int mw = blockIdx.x * 128 + w * 32;

    f32x16 Z16;
    #pragma unroll
    for (int r = 0; r < 16; r++) Z16[r] = 0.0f;

    bf16x8 qf = zero8();
    if (lane < 32)
        qf = *(const bf16x8*)(QB + ((size_t)b*NN + mw + l31)*8);

    f32x16 acc[2];
    acc[0] = Z16; acc[1] = Z16;

#define STAGE(bi, stq) do {                                                   \
    int n0_ = s*1152 + (stq)*64;                                              \
    _Pragma("unroll")                                                         \
    for (int i_ = 0; i_ < 2; i_++) {                                          \
        int p2_ = tid + i_*256;                                               \
        int c_ = p2_ >> 3, h7_ = p2_ & 7;                                     \
        int xc_ = h7_ ^ (c_ & 7);                                             \
        cp16((char*)vbuf[bi] + i_*4096 + w*1024,                              \
             VB + ((size_t)(b*64 + c_))*NN + n0_ + xc_*8);                    \
    }                                                                         \
    if (w == 0)                                                               \
        cp16((char*)klin[bi], KB + ((size_t)b*NN + n0_ + lane)*8);            \
} while (0)

    STAGE(0, 0);

    for (int st = 0; st < 18; st++) {
        int bi = st & 1;
        __syncthreads();
        if (st < 17) {
            if (bi == 0) STAGE(1, st+1); else STAGE(0, st+1);
        }
        const __bf16* kl = klin[bi];
        char* vb = (char*)vbuf[bi];

        #pragma unroll
        for (int nt = 0; nt < 2; nt++) {
            bf16x8 kfr = zero8();
            if (lane < 32)
                kfr = *(const bf16x8*)(kl + (nt*32 + l31)*8);

            f32x16 e = MFMA32(kfr, qf, Z16);
            float pf[16];
            #pragma unroll
            for (int r = 0; r < 16; r++) pf[r] = EXP2(e[r]);
            unsigned int u[8];
            #pragma unroll
            for (int q = 0; q < 8; q++) u[q] = pk2(pf[2*q], pf[2*q+1]);
            plane_swap(u[0], u[2]); plane_swap(u[1], u[3]);
            plane_swap(u[4], u[6]); plane_swap(u[5], u[7]);
            u32x4 t0 = {u[0], u[1], u[2], u[3]};
            u32x4 t1 = {u[4], u[5], u[6], u[7]};
            bf16x8 pa[2];
            pa[0] = __builtin_bit_cast(bf16x8, t0);
            pa[1] = __builtin_bit_cast(bf16x8, t1);

            #pragma unroll
            for (int ks = 0; ks < 2; ks++) {
                #pragma unroll
                for (int ct = 0; ct < 2; ct++) {
                    int c = ct*32 + l31;
                    bf16x8 bfr = *(const bf16x8*)(vb + c*128 +
                        ((nt*64 + ks*32 + h*16) ^ ((c & 7) << 4)));
                    acc[ct] = MFMA32(pa[ks], bfr, acc[ct]);
                }
            }
        }
    }

    if (parts != nullptr) {
        __bf16* pp = parts + ((size_t)(s*2 + b))*64*NN;
        #pragma unroll
        for (int ct = 0; ct < 2; ct++) {
            int c = ct*32 + l31;
            __bf16* row = pp + (size_t)c*NN + mw + 4*h;
            #pragma unroll
            for (int q = 0; q < 4; q++) {
                uint2 v2;
                v2.x = pk2(acc[ct][4*q],   acc[ct][4*q+1]);
                v2.y = pk2(acc[ct][4*q+2], acc[ct][4*q+3]);
                *(uint2*)(row + q*8) = v2;
            }
        }
    } else {
        #pragma unroll
        for (int ct = 0; ct < 2; ct++) {
            int c = ct*32 + l31;
            #pragma unroll
            for (int r = 0; r < 16; r++) {
                int m = mw + (r&3) + 8*(r>>2) + 4*h;
                atomicAdd(out + ((size_t)(b*64 + c))*NN + m, (float)acc[ct][r]);
            }
        }
    }
}

// ---------------- Kernel 6: out = x + sum_s parts[s] ----------------
// grid 576, block 256; thread owns 8 consecutive floats (576*256*8 = 1179648 = out_size).
__global__ __launch_bounds__(256) void reduce_kernel(
    const float* __restrict__ x, const __bf16* __restrict__ parts,
    float* __restrict__ out)
{
    size_t f0 = ((size_t)blockIdx.x*256 + threadIdx.x) * 8;
    float o[8];
    float4 a = *(const float4*)(x + f0);
    float4 c = *(const float4*)(x + f0 + 4);
    o[0]=a.x; o[1]=a.y; o[2]=a.z; o[3]=a.w;
    o[4]=c.x; o[5]=c.y; o[6]=c.z; o[7]=c.w;
    #pragma unroll
    for (int sIdx = 0; sIdx < 8; sIdx++) {
        bf16x8 p = *(const bf16x8*)(parts + (size_t)sIdx*(128*NN) + f0);
        #pragma unroll
        for (int j = 0; j < 8; j++) o[j] += (float)p[j];
    }
    float4 r0 = make_float4(o[0],o[1],o[2],o[3]);
    float4 r1 = make_float4(o[4],o[5],o[6],o[7]);
    *(float4*)(out + f0) = r0;
    *(float4*)(out + f0 + 4) = r1;
}

extern "C" void kernel_launch(void* const* d_in, const int* in_sizes, int n_in,
                              void* d_out, int out_size, void* d_ws, size_t ws_size,
                              hipStream_t stream) {
    const float* x     = (const float*)d_in[0];
    const float* Wq    = (const float*)d_in[1];
    const float* bq    = (const float*)d_in[2];
    const float* Wk    = (const float*)d_in[3];
    const float* bk    = (const float*)d_in[4];
    const float* Wv    = (const float*)d_in[5];
    const float* bv    = (const float*)d_in[6];
    const float* gamma = (const float*)d_in[7];
    float* out = (float*)d_out;
    char* ws   = (char*)d_ws;

    __bf16* QB = (__bf16*)(ws + OFF_QB);
    __bf16* KB = (__bf16*)(ws + OFF_KB);
    __bf16* VB = (__bf16*)(ws + OFF_VB);
    float*  Dp = (float*)(ws + OFF_DP);

    qkv_kernel<<<dim3(36, 2, 4), 256, 0, stream>>>(x, Wq, bq, Wk, bk, Wv, bv, QB, KB, VB);
    stats_kernel<<<dim3(288, 2, 2), 256, 0, stream>>>(QB, KB, Dp);
    fold_kernel<<<dim3(288, 2), 256, 0, stream>>>(Dp, gamma, VB);

    if (ws_size >= WS_NEED) {
        __bf16* parts = (__bf16*)(ws + OFF_PARTS);
        pv_kernel<<<dim3(72, 2, 8), 256, 0, stream>>>(QB, KB, VB, out, parts);
        reduce_kernel<<<dim3(576), 256, 0, stream>>>(x, parts, out);
    } else {
        init_kernel<<<dim3(1152), 256, 0, stream>>>(x, out);
        pv_kernel<<<dim3(72, 2, 8), 256, 0, stream>>>(QB, KB, VB, out, nullptr);
    }
}